// Round 14
// baseline (46.274 us; speedup 1.0000x reference)
//
#include <hip/hip_runtime.h>

#define TT 16384
#define DD 2048
#define EE 64

typedef __attribute__((ext_vector_type(8))) short bf16x8;
typedef __attribute__((ext_vector_type(8))) unsigned short ushort8;
typedef __attribute__((ext_vector_type(4))) float f32x4;

__device__ __forceinline__ unsigned short bf16_rne(float f) {
    unsigned u = __float_as_uint(f);
    return (unsigned short)((u + 0x7FFFu + ((u >> 16) & 1u)) >> 16);
}
__device__ __forceinline__ float bf16_f32(unsigned short h) {
    return __uint_as_float(((unsigned)h) << 16);
}
__device__ __forceinline__ unsigned cvt_pk(float lo, float hi) {
    unsigned r;
    asm("v_cvt_pk_bf16_f32 %0, %1, %2" : "=v"(r) : "v"(lo), "v"(hi));
    return r;  // low16 = bf16(lo), high16 = bf16(hi)
}
__device__ __forceinline__ bf16x8 pack4(unsigned a, unsigned b, unsigned c, unsigned d) {
    union { unsigned u[4]; bf16x8 v; } t;
    t.u[0] = a; t.u[1] = b; t.u[2] = c; t.u[3] = d;
    return t.v;
}
__device__ __forceinline__ void gload16(void* lds, const void* g) {
    __builtin_amdgcn_global_load_lds(
        (const __attribute__((address_space(1))) unsigned int*)g,
        (__attribute__((address_space(3))) unsigned int*)lds, 16, 0, 0);
}

// ---------------------------------------------------------------------------
// W [2048][64] f32 -> wpack: A-fragments in exact load order (R5 layout).
// wpack[K0][h][m][lane][j] = bf16 hi/lo of wg[(K0*32+(lane>>4)*8+j)*64 + m*16+(lane&15)]
__global__ __launch_bounds__(256)
void wconv(const float* __restrict__ wg, unsigned short* __restrict__ wpack) {
    const int t = (int)blockIdx.x * 256 + threadIdx.x;  // 32768 threads
    const int K0 = t >> 9, h = (t >> 8) & 1, m = (t >> 6) & 3, lane = t & 63;
    const int e = m * 16 + (lane & 15);
    const int ks = K0 * 32 + (lane >> 4) * 8;
    ushort8 v;
#pragma unroll
    for (int j = 0; j < 8; ++j) {
        const float f = wg[(size_t)(ks + j) * EE + e];
        const unsigned short hi = bf16_rne(f);
        v[j] = h ? bf16_rne(f - bf16_f32(hi)) : hi;
    }
    *(ushort8*)(wpack + ((size_t)(K0 * 8 + h * 4 + m) * 64 + lane) * 8) = v;
}

// ---------------------------------------------------------------------------
// R13's gate with ONE delta: per-wave-private LDS staging rings and NO
// barriers in the K-loop.  Wave (tg,q) stages its own 16 rows x 32 k per
// step (2 x 1 KB gload16, 128-B source segments, chunk swizzle) into its own
// 3-slot ring and consumes only that.  Per-wave FIFO vmcnt counts identical
// to R5 (2 stage + 8 W per step, vmcnt(10) steady-state).  Waves drift
// freely; block syncs only once before the K-reduce.  Grid 512 = 2 blocks/CU.
__global__ __launch_bounds__(512, 4)
void gate_fused(const float* __restrict__ x, const unsigned short* __restrict__ wpack,
                const float* __restrict__ loads, float* __restrict__ out,
                float* __restrict__ binpart) {
    __shared__ __align__(16) float arena[12288];  // 48 KB: 8 waves x 3 x 512 f
    __shared__ float bins[2][64];

    const int tid = threadIdx.x, lane = tid & 63, w = tid >> 6;
    const int tg = w >> 2, q = w & 3;   // token-group, K-quarter
    const int tb = (int)blockIdx.x;

    f32x4 acc[4] = {{0,0,0,0},{0,0,0,0},{0,0,0,0},{0,0,0,0}};

    // wave-private ring: stage this wave's 16 rows x 32 k for step s (2 KB)
    auto stage_x = [&](int s, float* rb) {
#pragma unroll
        for (int i = 0; i < 2; ++i) {
            const int rowp = lane >> 3;       // 0..7
            const int r = i * 8 + rowp;       // row within tg: 0..15
            const int c = (lane & 7) ^ rowp;  // source-side chunk swizzle
            gload16(rb + i * 256,
                    x + (size_t)(tb * 32 + tg * 16 + r) * DD + q * 512 + s * 32 + c * 4);
        }
    };
    auto loadW = [&](int t, bf16x8 (&wh)[4], bf16x8 (&wl)[4]) {
        const unsigned short* base = wpack + (size_t)(q * 16 + t) * 4096 + lane * 8;
#pragma unroll
        for (int m = 0; m < 4; ++m) {
            wh[m] = *(const bf16x8*)(base + (size_t)m * 512);
            wl[m] = *(const bf16x8*)(base + (size_t)(4 + m) * 512);
        }
    };
    auto compute = [&](const float* rb, bf16x8 (&wh)[4], bf16x8 (&wl)[4]) {
        const int r = lane & 15;
        const int kgc = (lane >> 4) << 1;
        const int sw = r & 7;
        const f32x4 va = *(const f32x4*)(rb + r * 32 + ((kgc) ^ sw) * 4);
        const f32x4 vb = *(const f32x4*)(rb + r * 32 + ((kgc + 1) ^ sw) * 4);
        const float cf[8] = {va.x, va.y, va.z, va.w, vb.x, vb.y, vb.z, vb.w};
        unsigned ph[4], pl[4];
#pragma unroll
        for (int j = 0; j < 4; ++j) {
            ph[j] = cvt_pk(cf[2 * j], cf[2 * j + 1]);
            const float h0 = __uint_as_float(ph[j] << 16);
            const float h1 = __uint_as_float(ph[j] & 0xFFFF0000u);
            pl[j] = cvt_pk(cf[2 * j] - h0, cf[2 * j + 1] - h1);
        }
        const bf16x8 bhi = pack4(ph[0], ph[1], ph[2], ph[3]);
        const bf16x8 blo = pack4(pl[0], pl[1], pl[2], pl[3]);
#pragma unroll
        for (int m = 0; m < 4; ++m) {
            acc[m] = __builtin_amdgcn_mfma_f32_16x16x32_bf16(wh[m], bhi, acc[m], 0, 0, 0);
            acc[m] = __builtin_amdgcn_mfma_f32_16x16x32_bf16(wh[m], blo, acc[m], 0, 0, 0);
            acc[m] = __builtin_amdgcn_mfma_f32_16x16x32_bf16(wl[m], bhi, acc[m], 0, 0, 0);
        }
    };

    float* ring = arena + (size_t)w * 1536;
    float *p0 = ring, *p1 = ring + 512, *p2 = ring + 1024;
    bf16x8 whA[4], wlA[4], whB[4], wlB[4];

    stage_x(0, p0);
    stage_x(1, p1);
    loadW(0, whA, wlA);
    asm volatile("s_waitcnt vmcnt(10)" ::: "memory");  // drain st0

#pragma unroll 1
    for (int s = 0; s < 14; s += 2) {
        stage_x(s + 2, p2);
        loadW(s + 1, whB, wlB);
        compute(p0, whA, wlA);
        asm volatile("s_waitcnt vmcnt(10)" ::: "memory");  // drain st(s+1)+W(s)
        { float* t_ = p0; p0 = p1; p1 = p2; p2 = t_; }

        stage_x(s + 3, p2);
        loadW(s + 2, whA, wlA);
        compute(p0, whB, wlB);
        asm volatile("s_waitcnt vmcnt(10)" ::: "memory");
        { float* t_ = p0; p0 = p1; p1 = p2; p2 = t_; }
    }
    loadW(15, whB, wlB);
    compute(p0, whA, wlA);               // step 14
    asm volatile("s_waitcnt vmcnt(8)" ::: "memory");   // drain st15 + W14
    compute(p1, whB, wlB);               // step 15

    // ---- K-split reduction through arena overlay (stride 20: no conflicts)
    __syncthreads();                     // all waves done with their rings
    float* accb = arena;                 // [3 q'][2 tg][64 lane][20]
    if (q != 0) {
#pragma unroll
        for (int m = 0; m < 4; ++m)
            *(f32x4*)(accb + ((size_t)((q - 1) * 128 + tg * 64 + lane) * 20 + m * 4)) = acc[m];
    }
    __syncthreads();
    if (q != 0) return;

    f32x4 r[4];
#pragma unroll
    for (int m = 0; m < 4; ++m) {
        f32x4 s_ = acc[m];
#pragma unroll
        for (int qq = 0; qq < 3; ++qq) {
            const f32x4 t_ =
                *(const f32x4*)(accb + ((size_t)(qq * 128 + tg * 64 + lane) * 20 + m * 4));
            s_.x += t_.x; s_.y += t_.y; s_.z += t_.z; s_.w += t_.w;
        }
        r[m] = s_;
    }

    // ---- top-2 (biased): lane holds e = m*16 + (lane>>4)*4 + rr ----------
    const int col = lane & 15;
    const int tok = tb * 32 + tg * 16 + col;
    const int erow = (lane >> 4) * 4;
    float v1 = -3.4e38f, u1 = 0.0f, v2 = -3.4e38f, u2 = 0.0f;
    int i1 = 0x7fffffff, i2 = 0x7fffffff;
#pragma unroll
    for (int m = 0; m < 4; ++m)
#pragma unroll
        for (int rr = 0; rr < 4; ++rr) {
            const int e = m * 16 + erow + rr;
            const float u = r[m][rr];
            const float b = u - (loads[e] - 0.015625f) * 2.0f;
            if ((b > v1) || (b == v1 && e < i1)) {
                v2 = v1; u2 = u1; i2 = i1;
                v1 = b;  u1 = u;  i1 = e;
            } else if ((b > v2) || (b == v2 && e < i2)) {
                v2 = b; u2 = u; i2 = e;
            }
        }
#pragma unroll
    for (int s = 0; s < 2; ++s) {
        const int mask = 16 << s;
        const float ov1 = __shfl_xor(v1, mask), ou1 = __shfl_xor(u1, mask);
        const float ov2 = __shfl_xor(v2, mask), ou2 = __shfl_xor(u2, mask);
        const int oi1 = __shfl_xor(i1, mask), oi2 = __shfl_xor(i2, mask);
        if ((ov1 > v1) || (ov1 == v1 && oi1 < i1)) {
            if ((v1 > ov2) || (v1 == ov2 && i1 < oi2)) { v2 = v1; u2 = u1; i2 = i1; }
            else                                        { v2 = ov2; u2 = ou2; i2 = oi2; }
            v1 = ov1; u1 = ou1; i1 = oi1;
        } else if ((ov1 > v2) || (ov1 == v2 && oi1 < i2)) {
            v2 = ov1; u2 = ou1; i2 = oi1;
        }
    }

    bins[tg][lane] = 0.0f;
    if (lane < 16) {
        const float mx = fmaxf(u1, u2);
        const float e1 = __expf(u1 - mx), e2 = __expf(u2 - mx);
        const float w1 = e1 / (e1 + e2), w2 = e2 / (e1 + e2);
        *(float2*)(out + 2 * tok) = make_float2(w1, w2);
        *(float2*)(out + 2 * TT + 2 * tok) = make_float2((float)i1, (float)i2);
        atomicAdd(&bins[tg][i1], w1);
        atomicAdd(&bins[tg][i2], w2);
    }
    binpart[(size_t)(tb * 2 + tg) * 64 + lane] = bins[tg][lane];
}

// ---------------------------------------------------------------------------
// Merged finalize (R13): 1 block x 1024 thr, deterministic fixed-order tree.
__global__ __launch_bounds__(1024)
void finalize(const float* __restrict__ binpart, const float* __restrict__ loads,
              float* __restrict__ out) {
    __shared__ float p[16][64];
    const int e = threadIdx.x & 63, sub = threadIdx.x >> 6;  // sub 0..15
    float s = 0.0f;
#pragma unroll
    for (int r = 0; r < 64; ++r)
        s += binpart[(size_t)(sub * 64 + r) * 64 + e];
    p[sub][e] = s;
    __syncthreads();
    if (sub == 0) {
        float tot = 0.0f;
#pragma unroll
        for (int k = 0; k < 16; ++k) tot += p[k][e];
        out[4 * TT + e] = 0.9f * loads[e] + 0.1f * (tot * (1.0f / 16384.0f));
    }
}

// ---------------------------------------------------------------------------
extern "C" void kernel_launch(void* const* d_in, const int* in_sizes, int n_in,
                              void* d_out, int out_size, void* d_ws, size_t ws_size,
                              hipStream_t stream) {
    const float* x = (const float*)d_in[0];      // [16384, 2048]
    const float* wg = (const float*)d_in[1];     // [2048, 64]
    const float* loads = (const float*)d_in[2];  // [64]
    float* out = (float*)d_out;

    unsigned short* wpack = (unsigned short*)d_ws;               // 512 KB
    float* binpart = (float*)(wpack + (size_t)64 * 8 * 64 * 8);  // [1024][64]

    hipLaunchKernelGGL(wconv, dim3(128), dim3(256), 0, stream, wg, wpack);
    hipLaunchKernelGGL(gate_fused, dim3(512), dim3(512), 0, stream,
                       x, wpack, loads, out, binpart);
    hipLaunchKernelGGL(finalize, dim3(1), dim3(1024), 0, stream,
                       binpart, loads, out);
}

// Round 15
// 45.168 us; speedup vs baseline: 1.0245x; 1.0245x over previous
//
#include <hip/hip_runtime.h>

#define TT 16384
#define DD 2048
#define EE 64

typedef __attribute__((ext_vector_type(8))) short bf16x8;
typedef __attribute__((ext_vector_type(8))) unsigned short ushort8;
typedef __attribute__((ext_vector_type(4))) float f32x4;

__device__ __forceinline__ unsigned short bf16_rne(float f) {
    unsigned u = __float_as_uint(f);
    return (unsigned short)((u + 0x7FFFu + ((u >> 16) & 1u)) >> 16);
}
__device__ __forceinline__ float bf16_f32(unsigned short h) {
    return __uint_as_float(((unsigned)h) << 16);
}
__device__ __forceinline__ unsigned cvt_pk(float lo, float hi) {
    unsigned r;
    asm("v_cvt_pk_bf16_f32 %0, %1, %2" : "=v"(r) : "v"(lo), "v"(hi));
    return r;
}
__device__ __forceinline__ bf16x8 pack4(unsigned a, unsigned b, unsigned c, unsigned d) {
    union { unsigned u[4]; bf16x8 v; } t;
    t.u[0] = a; t.u[1] = b; t.u[2] = c; t.u[3] = d;
    return t.v;
}
__device__ __forceinline__ void gload16(void* lds, const void* g) {
    __builtin_amdgcn_global_load_lds(
        (const __attribute__((address_space(1))) unsigned int*)g,
        (__attribute__((address_space(3))) unsigned int*)lds, 16, 0, 0);
}
// Forced-register 16B global load: compiler cannot collapse the prefetch
// depth because it doesn't own the asm output registers.
__device__ __forceinline__ void ld16(bf16x8& d, const void* p) {
    asm volatile("global_load_dwordx4 %0, %1, off"
                 : "=&v"(d) : "v"(p) : "memory");
}
#define SB0() __builtin_amdgcn_sched_barrier(0)

// ---------------------------------------------------------------------------
// W [2048][64] f32 -> wpack: A-fragments in exact load order (R5 layout).
// wpack[K0][h][m][lane][j] = bf16 hi/lo of wg[(K0*32+(lane>>4)*8+j)*64 + m*16+(lane&15)]
__global__ __launch_bounds__(256)
void wconv(const float* __restrict__ wg, unsigned short* __restrict__ wpack) {
    const int t = (int)blockIdx.x * 256 + threadIdx.x;  // 32768 threads
    const int K0 = t >> 9, h = (t >> 8) & 1, m = (t >> 6) & 3, lane = t & 63;
    const int e = m * 16 + (lane & 15);
    const int ks = K0 * 32 + (lane >> 4) * 8;
    ushort8 v;
#pragma unroll
    for (int j = 0; j < 8; ++j) {
        const float f = wg[(size_t)(ks + j) * EE + e];
        const unsigned short hi = bf16_rne(f);
        v[j] = h ? bf16_rne(f - bf16_f32(hi)) : hi;
    }
    *(ushort8*)(wpack + ((size_t)(K0 * 8 + h * 4 + m) * 64 + lane) * 8) = v;
}

// ---------------------------------------------------------------------------
// Barrier-free fused gate (R14 structure) with FORCED-REGISTER W prefetch.
// Block = 256 thr = 4 waves on the same 16 tokens; wave q owns K-quarter
// [q*512,+512), 16 steps x 32 k.  Grid 1024 (16 tok/block).
// x: per-wave-private 3-slot LDS ring via global_load_lds (2 x 1 KB/step).
// W: inline-asm global_load_dwordx4 into named A/B register slots, issued one
// step ahead; per-wave FIFO counted waits (vmcnt(12) steady) + sched_barrier
// fences (rule 18).  x 2 steps in flight, W 1 step, no block barriers.
__global__ __launch_bounds__(256, 4)
void gate_fused(const float* __restrict__ x, const unsigned short* __restrict__ wpack,
                const float* __restrict__ loads, float* __restrict__ out,
                float* __restrict__ binpart) {
    __shared__ __align__(16) float arena[6144];  // 24 KB: 4 waves x 3 x 512 f
    __shared__ float bins[64];

    const int tid = threadIdx.x, lane = tid & 63, q = tid >> 6;  // K-quarter
    const int tb = (int)blockIdx.x;

    f32x4 acc[4] = {{0,0,0,0},{0,0,0,0},{0,0,0,0},{0,0,0,0}};

    // wave-private ring: stage 16 rows x 32 k for step s (2 x 1 KB)
    auto stage_x = [&](int s, float* rb) {
#pragma unroll
        for (int i = 0; i < 2; ++i) {
            const int rowp = lane >> 3;       // 0..7
            const int r = i * 8 + rowp;       // row 0..15
            const int c = (lane & 7) ^ rowp;  // source-side chunk swizzle
            gload16(rb + i * 256,
                    x + (size_t)(tb * 16 + r) * DD + q * 512 + s * 32 + c * 4);
        }
    };
    auto asmW = [&](int t, bf16x8 (&wh)[4], bf16x8 (&wl)[4]) {
        const unsigned short* base = wpack + (size_t)(q * 16 + t) * 4096 + lane * 8;
#pragma unroll
        for (int m = 0; m < 4; ++m) ld16(wh[m], base + (size_t)m * 512);
#pragma unroll
        for (int m = 0; m < 4; ++m) ld16(wl[m], base + (size_t)(4 + m) * 512);
    };
    auto compute = [&](const float* rb, bf16x8 (&wh)[4], bf16x8 (&wl)[4]) {
        const int r = lane & 15;
        const int kgc = (lane >> 4) << 1;
        const int sw = r & 7;
        const f32x4 va = *(const f32x4*)(rb + r * 32 + ((kgc) ^ sw) * 4);
        const f32x4 vb = *(const f32x4*)(rb + r * 32 + ((kgc + 1) ^ sw) * 4);
        const float cf[8] = {va.x, va.y, va.z, va.w, vb.x, vb.y, vb.z, vb.w};
        unsigned ph[4], pl[4];
#pragma unroll
        for (int j = 0; j < 4; ++j) {
            ph[j] = cvt_pk(cf[2 * j], cf[2 * j + 1]);
            const float h0 = __uint_as_float(ph[j] << 16);
            const float h1 = __uint_as_float(ph[j] & 0xFFFF0000u);
            pl[j] = cvt_pk(cf[2 * j] - h0, cf[2 * j + 1] - h1);
        }
        const bf16x8 bhi = pack4(ph[0], ph[1], ph[2], ph[3]);
        const bf16x8 blo = pack4(pl[0], pl[1], pl[2], pl[3]);
#pragma unroll
        for (int m = 0; m < 4; ++m) {
            acc[m] = __builtin_amdgcn_mfma_f32_16x16x32_bf16(wh[m], bhi, acc[m], 0, 0, 0);
            acc[m] = __builtin_amdgcn_mfma_f32_16x16x32_bf16(wh[m], blo, acc[m], 0, 0, 0);
            acc[m] = __builtin_amdgcn_mfma_f32_16x16x32_bf16(wl[m], bhi, acc[m], 0, 0, 0);
        }
    };

    float* ring = arena + (size_t)q * 1536;
    float *p0 = ring, *p1 = ring + 512, *p2 = ring + 1024;
    bf16x8 whA[4], wlA[4], whB[4], wlB[4];

    // prologue FIFO: st0(2) W0(8) st1(2) W1(8) st2(2) = 22
    stage_x(0, p0); SB0();
    asmW(0, whA, wlA); SB0();
    stage_x(1, p1); SB0();
    asmW(1, whB, wlB); SB0();
    stage_x(2, p2); SB0();
    asm volatile("s_waitcnt vmcnt(12)" ::: "memory");  // drain st0+W0
    SB0();
    compute(p0, whA, wlA);                             // step 0
    { float* t_ = p0; p0 = p1; p1 = p2; p2 = t_; }

#pragma unroll 1
    for (int s = 0; s < 12; s += 2) {
        asmW(s + 2, whA, wlA); SB0();
        stage_x(s + 3, p2); SB0();
        asm volatile("s_waitcnt vmcnt(12)" ::: "memory");  // drain st(s+1)+W(s+1)
        SB0();
        compute(p0, whB, wlB);                             // step s+1
        { float* t_ = p0; p0 = p1; p1 = p2; p2 = t_; }

        asmW(s + 3, whB, wlB); SB0();
        stage_x(s + 4, p2); SB0();
        asm volatile("s_waitcnt vmcnt(12)" ::: "memory");  // drain st(s+2)+W(s+2)
        SB0();
        compute(p0, whA, wlA);                             // step s+2
        { float* t_ = p0; p0 = p1; p1 = p2; p2 = t_; }
    }
    // in flight here: st13(2) W13(8) st14(2) = 12
    asmW(14, whA, wlA); SB0();
    stage_x(15, p2); SB0();
    asm volatile("s_waitcnt vmcnt(12)" ::: "memory");      // drain st13+W13
    SB0();
    compute(p0, whB, wlB);                                 // step 13
    { float* t_ = p0; p0 = p1; p1 = p2; p2 = t_; }

    asmW(15, whB, wlB); SB0();
    asm volatile("s_waitcnt vmcnt(10)" ::: "memory");      // drain st14+W14
    SB0();
    compute(p0, whA, wlA);                                 // step 14
    { float* t_ = p0; p0 = p1; p1 = p2; p2 = t_; }
    asm volatile("s_waitcnt vmcnt(0)" ::: "memory");       // drain st15+W15
    SB0();
    compute(p0, whB, wlB);                                 // step 15

    // ---- K-split reduction through arena overlay (stride 20, 16 f/lane) --
    __syncthreads();                     // all waves done with their rings
    float* accb = arena;                 // [3 q'][64 lane][20]
    if (q != 0) {
#pragma unroll
        for (int m = 0; m < 4; ++m)
            *(f32x4*)(accb + ((size_t)((q - 1) * 64 + lane) * 20 + m * 4)) = acc[m];
    }
    __syncthreads();
    if (q != 0) return;

    f32x4 r[4];
#pragma unroll
    for (int m = 0; m < 4; ++m) {
        f32x4 s_ = acc[m];
#pragma unroll
        for (int qq = 0; qq < 3; ++qq) {
            const f32x4 t_ =
                *(const f32x4*)(accb + ((size_t)(qq * 64 + lane) * 20 + m * 4));
            s_.x += t_.x; s_.y += t_.y; s_.z += t_.z; s_.w += t_.w;
        }
        r[m] = s_;
    }

    // ---- top-2 (biased): lane holds e = m*16 + (lane>>4)*4 + rr ----------
    const int col = lane & 15;
    const int tok = tb * 16 + col;
    const int erow = (lane >> 4) * 4;
    float v1 = -3.4e38f, u1 = 0.0f, v2 = -3.4e38f, u2 = 0.0f;
    int i1 = 0x7fffffff, i2 = 0x7fffffff;
#pragma unroll
    for (int m = 0; m < 4; ++m)
#pragma unroll
        for (int rr = 0; rr < 4; ++rr) {
            const int e = m * 16 + erow + rr;
            const float u = r[m][rr];
            const float b = u - (loads[e] - 0.015625f) * 2.0f;
            if ((b > v1) || (b == v1 && e < i1)) {
                v2 = v1; u2 = u1; i2 = i1;
                v1 = b;  u1 = u;  i1 = e;
            } else if ((b > v2) || (b == v2 && e < i2)) {
                v2 = b; u2 = u; i2 = e;
            }
        }
#pragma unroll
    for (int s = 0; s < 2; ++s) {
        const int mask = 16 << s;
        const float ov1 = __shfl_xor(v1, mask), ou1 = __shfl_xor(u1, mask);
        const float ov2 = __shfl_xor(v2, mask), ou2 = __shfl_xor(u2, mask);
        const int oi1 = __shfl_xor(i1, mask), oi2 = __shfl_xor(i2, mask);
        if ((ov1 > v1) || (ov1 == v1 && oi1 < i1)) {
            if ((v1 > ov2) || (v1 == ov2 && i1 < oi2)) { v2 = v1; u2 = u1; i2 = i1; }
            else                                        { v2 = ov2; u2 = ou2; i2 = oi2; }
            v1 = ov1; u1 = ou1; i1 = oi1;
        } else if ((ov1 > v2) || (ov1 == v2 && oi1 < i2)) {
            v2 = ov1; u2 = ou1; i2 = oi1;
        }
    }

    bins[lane] = 0.0f;
    if (lane < 16) {
        const float mx = fmaxf(u1, u2);
        const float e1 = __expf(u1 - mx), e2 = __expf(u2 - mx);
        const float w1 = e1 / (e1 + e2), w2 = e2 / (e1 + e2);
        *(float2*)(out + 2 * tok) = make_float2(w1, w2);
        *(float2*)(out + 2 * TT + 2 * tok) = make_float2((float)i1, (float)i2);
        atomicAdd(&bins[i1], w1);
        atomicAdd(&bins[i2], w2);
    }
    binpart[(size_t)tb * 64 + lane] = bins[lane];
}

// ---------------------------------------------------------------------------
// Merged finalize (R13): 1 block x 1024 thr, deterministic fixed-order tree.
__global__ __launch_bounds__(1024)
void finalize(const float* __restrict__ binpart, const float* __restrict__ loads,
              float* __restrict__ out) {
    __shared__ float p[16][64];
    const int e = threadIdx.x & 63, sub = threadIdx.x >> 6;  // sub 0..15
    float s = 0.0f;
#pragma unroll
    for (int r = 0; r < 64; ++r)
        s += binpart[(size_t)(sub * 64 + r) * 64 + e];
    p[sub][e] = s;
    __syncthreads();
    if (sub == 0) {
        float tot = 0.0f;
#pragma unroll
        for (int k = 0; k < 16; ++k) tot += p[k][e];
        out[4 * TT + e] = 0.9f * loads[e] + 0.1f * (tot * (1.0f / 16384.0f));
    }
}

// ---------------------------------------------------------------------------
extern "C" void kernel_launch(void* const* d_in, const int* in_sizes, int n_in,
                              void* d_out, int out_size, void* d_ws, size_t ws_size,
                              hipStream_t stream) {
    const float* x = (const float*)d_in[0];      // [16384, 2048]
    const float* wg = (const float*)d_in[1];     // [2048, 64]
    const float* loads = (const float*)d_in[2];  // [64]
    float* out = (float*)d_out;

    unsigned short* wpack = (unsigned short*)d_ws;               // 512 KB
    float* binpart = (float*)(wpack + (size_t)64 * 8 * 64 * 8);  // [1024][64]

    hipLaunchKernelGGL(wconv, dim3(128), dim3(256), 0, stream, wg, wpack);
    hipLaunchKernelGGL(gate_fused, dim3(1024), dim3(256), 0, stream,
                       x, wpack, loads, out, binpart);
    hipLaunchKernelGGL(finalize, dim3(1), dim3(1024), 0, stream,
                       binpart, loads, out);
}